// Round 4
// baseline (131.523 us; speedup 1.0000x reference)
//
#include <hip/hip_runtime.h>

#define PAD 3
#define HH 320
#define WW 1024
#define BB 8
#define TW 256          // tile width (cols per block); 64 lanes x 4-px strips
#define TH 4            // output rows per block (1 per wave)
#define SROWS 7         // staged support rows = TH + 3 (half-space: only down)
#define SCOLS 264       // staged cols = TW + 4 left + 4 right
#define NC4 66          // SCOLS / 4

#define NIN ((HH - 2*PAD) * (WW - 2*PAD))
#define OUT_SCALE (1.0 / (49.0 * (double)BB * (double)HH * (double)WW))
#define C0 ((float)(48.0 * (double)BB * (double)NIN * OUT_SCALE))
#define NEG_SCALE ((float)(-0.1 * OUT_SCALE))

__global__ __launch_bounds__(256) void ternary_loss_kernel(
    const float* __restrict__ x, const float* __restrict__ y,
    float* __restrict__ out)
{
    __shared__ float sI[2][SROWS][SCOLS];   // [tensor][row][col], 14.8 KB
    __shared__ float wave_sums[4];

    const int tile_j = blockIdx.x * TW;
    const int tile_i = blockIdx.y * TH;
    const int b      = blockIdx.z;
    const int tx  = threadIdx.x;            // 0..63
    const int wv  = threadIdx.y;            // 0..3 (wave id = output row)
    const int tid = wv * 64 + tx;

    const float* xb = x + (size_t)b * 3 * HH * WW;
    const float* yb = y + (size_t)b * 3 * HH * WW;

    // ---- stage: 2 tensors x 7 rows x 66 float4 (mean of 3 channels) ----
    // every float4 slot is fully inside or fully outside the image
    for (int idx = tid; idx < 2 * SROWS * NC4; idx += 256) {
        int tsel = idx / (SROWS * NC4);
        int rem  = idx - tsel * (SROWS * NC4);
        int r    = rem / NC4;
        int c4   = rem - r * NC4;
        int gr = tile_i + r;                // never negative
        int gc = tile_j - 4 + 4 * c4;
        float4 v = make_float4(0.f, 0.f, 0.f, 0.f);
        if (gr < HH && gc >= 0 && gc + 3 < WW) {
            const float* p = (tsel ? yb : xb) + (size_t)gr * WW + gc;
            float4 a = *(const float4*)p;
            float4 c1 = *(const float4*)(p + (size_t)HH * WW);
            float4 c2 = *(const float4*)(p + 2 * (size_t)HH * WW);
            v.x = (a.x + c1.x + c2.x) * (1.f / 3.f);
            v.y = (a.y + c1.y + c2.y) * (1.f / 3.f);
            v.z = (a.z + c1.z + c2.z) * (1.f / 3.f);
            v.w = (a.w + c1.w + c2.w) * (1.f / 3.f);
        }
        *(float4*)&sI[tsel][r][4 * c4] = v;
    }
    __syncthreads();

    // ---- compute: this wave owns output row gi = tile_i + wv ----
    const int gi = tile_i + wv;
    const int j0 = tile_j + 4 * tx;   // global col of strip pixel p=0
    const int lc = 4 * tx;            // LDS col of (j0 - 4)

    // column-interior flags for global cols j0-3 .. j0+6  (index d: col j0+d-3)
    float colf[10];
    #pragma unroll
    for (int d = 0; d < 10; ++d) {
        int col = j0 + d - 3;
        colf[d] = (col >= PAD && col < WW - PAD) ? 1.f : 0.f;
    }
    float rowf[4];
    #pragma unroll
    for (int di = 0; di < 4; ++di) {
        int rr = gi + di;
        rowf[di] = (rr >= PAD && rr < HH - PAD) ? 1.f : 0.f;
    }
    float mc[4];
    #pragma unroll
    for (int p = 0; p < 4; ++p) mc[p] = rowf[0] * colf[p + 3];

    // centers: support row 0 (staged row wv), cols lc..lc+11 -> px at f[4..7]
    float cx[4], cy[4];
    {
        float4 xa = *(const float4*)&sI[0][wv][lc + 4];
        float4 ya = *(const float4*)&sI[1][wv][lc + 4];
        cx[0] = xa.x; cx[1] = xa.y; cx[2] = xa.z; cx[3] = xa.w;
        cy[0] = ya.x; cy[1] = ya.y; cy[2] = ya.z; cy[3] = ya.w;
    }

    float acc = 0.f;    // sum of w * rcp(0.1 + t^2)

    #pragma unroll
    for (int di = 0; di <= 3; ++di) {
        // load support row wv+di: 12 floats per tensor (3 x b128)
        float rx[12], ry[12];
        {
            float4 a0 = *(const float4*)&sI[0][wv + di][lc];
            float4 a1 = *(const float4*)&sI[0][wv + di][lc + 4];
            float4 a2 = *(const float4*)&sI[0][wv + di][lc + 8];
            rx[0]=a0.x; rx[1]=a0.y; rx[2]=a0.z; rx[3]=a0.w;
            rx[4]=a1.x; rx[5]=a1.y; rx[6]=a1.z; rx[7]=a1.w;
            rx[8]=a2.x; rx[9]=a2.y; rx[10]=a2.z; rx[11]=a2.w;
            float4 b0 = *(const float4*)&sI[1][wv + di][lc];
            float4 b1 = *(const float4*)&sI[1][wv + di][lc + 4];
            float4 b2 = *(const float4*)&sI[1][wv + di][lc + 8];
            ry[0]=b0.x; ry[1]=b0.y; ry[2]=b0.z; ry[3]=b0.w;
            ry[4]=b1.x; ry[5]=b1.y; ry[6]=b1.z; ry[7]=b1.w;
            ry[8]=b2.x; ry[9]=b2.y; ry[10]=b2.z; ry[11]=b2.w;
        }
        #pragma unroll
        for (int dj = -3; dj <= 3; ++dj) {
            if (di == 0 && dj <= 0) continue;   // half-space: 24 offsets
            #pragma unroll
            for (int p = 0; p < 4; ++p) {
                float dx = rx[4 + p + dj] - cx[p];
                float gx = dx * __builtin_amdgcn_rsqf(fmaf(dx, dx, 0.81f));
                float dy = ry[4 + p + dj] - cy[p];
                float gy = dy * __builtin_amdgcn_rsqf(fmaf(dy, dy, 0.81f));
                float t  = gx - gy;
                float r  = __builtin_amdgcn_rcpf(fmaf(t, t, 0.1f));
                float w  = fmaf(rowf[di], colf[p + dj + 3], mc[p]);
                acc = fmaf(w, r, acc);
            }
        }
    }

    // ---- reduction: wave shuffle -> LDS across 4 waves -> one atomic ----
    #pragma unroll
    for (int off = 32; off > 0; off >>= 1)
        acc += __shfl_down(acc, off, 64);
    if (tx == 0) wave_sums[wv] = acc;
    __syncthreads();
    if (tid == 0) {
        float total = (wave_sums[0] + wave_sums[1] + wave_sums[2] + wave_sums[3]) * NEG_SCALE;
        if (blockIdx.x == 0 && blockIdx.y == 0 && blockIdx.z == 0)
            total += C0;                       // analytic sum(w)*1 term, once
        atomicAdd(out, total);
    }
}

extern "C" void kernel_launch(void* const* d_in, const int* in_sizes, int n_in,
                              void* d_out, int out_size, void* d_ws, size_t ws_size,
                              hipStream_t stream) {
    const float* x = (const float*)d_in[0];
    const float* y = (const float*)d_in[1];
    float* out = (float*)d_out;

    hipMemsetAsync(out, 0, sizeof(float), stream);

    dim3 grid(WW / TW, HH / TH, BB);   // 4 x 80 x 8 = 2560 blocks
    dim3 block(64, 4, 1);
    ternary_loss_kernel<<<grid, block, 0, stream>>>(x, y, out);
}